// Round 6
// baseline (668.703 us; speedup 1.0000x reference)
//
#include <hip/hip_runtime.h>
#include <hip/hip_cooperative_groups.h>
#include <math.h>

namespace cg = cooperative_groups;

#define NE 320000
#define NN 20000
#define NQ 200000

struct Prm {
  const float *x, *L0, *L1;
  const int *ei, *te;
  const float *W1, *b1, *W2, *b2, *wsim, *embs, *wod, *wL0, *wL1, *lin1W, *lin1b, *linW, *linb;
  float *out;
  int *ideg, *start, *cursor, *csr;
  float *dinv, *h1raw, *h1, *g, *L0r, *L1r, *Ab, *Bb, *Ab2, *Mm, *Ee, *semb;
};

// ---- 512^3 f32 GEMM tile (C = A@A), 64x64, 4x4 microtile; smem use = 8704 B ----
__device__ __forceinline__ void gemm512_body(char* smem, const float* __restrict__ A,
                                             float* __restrict__ C, int bb) {
  float (*As)[68] = (float(*)[68])smem;
  float (*Bs)[68] = (float(*)[68])(smem + 16 * 68 * 4);
  int tid = threadIdx.x;
  int tx = tid & 15, ty = tid >> 4;
  int brow = (bb >> 3) * 64;
  int bcol = (bb & 7) * 64;
  float c[4][4] = {};
  for (int k0 = 0; k0 < 512; k0 += 16) {
#pragma unroll
    for (int t = 0; t < 4; t++) {
      int idx = tid * 4 + t;
      int r = idx >> 4, cc = idx & 15;
      As[cc][r] = A[(size_t)(brow + r) * 512 + k0 + cc];
      int r2 = idx >> 6, c2 = idx & 63;
      Bs[r2][c2] = A[(size_t)(k0 + r2) * 512 + bcol + c2];
    }
    __syncthreads();
#pragma unroll
    for (int k = 0; k < 16; k++) {
      float a0 = As[k][ty * 4 + 0], a1 = As[k][ty * 4 + 1];
      float a2 = As[k][ty * 4 + 2], a3 = As[k][ty * 4 + 3];
      float b0 = Bs[k][tx * 4 + 0], b1 = Bs[k][tx * 4 + 1];
      float b2 = Bs[k][tx * 4 + 2], b3 = Bs[k][tx * 4 + 3];
      c[0][0] = fmaf(a0, b0, c[0][0]); c[0][1] = fmaf(a0, b1, c[0][1]);
      c[0][2] = fmaf(a0, b2, c[0][2]); c[0][3] = fmaf(a0, b3, c[0][3]);
      c[1][0] = fmaf(a1, b0, c[1][0]); c[1][1] = fmaf(a1, b1, c[1][1]);
      c[1][2] = fmaf(a1, b2, c[1][2]); c[1][3] = fmaf(a1, b3, c[1][3]);
      c[2][0] = fmaf(a2, b0, c[2][0]); c[2][1] = fmaf(a2, b1, c[2][1]);
      c[2][2] = fmaf(a2, b2, c[2][2]); c[2][3] = fmaf(a2, b3, c[2][3]);
      c[3][0] = fmaf(a3, b0, c[3][0]); c[3][1] = fmaf(a3, b1, c[3][1]);
      c[3][2] = fmaf(a3, b2, c[3][2]); c[3][3] = fmaf(a3, b3, c[3][3]);
    }
    __syncthreads();
  }
#pragma unroll
  for (int i = 0; i < 4; i++)
#pragma unroll
    for (int j = 0; j < 4; j++)
      C[(size_t)(brow + ty * 4 + i) * 512 + bcol + tx * 4 + j] = c[i][j];
}

// ---- skinny GEMM tile: Y = X@W, W staged in LDS in <=16KB K-chunks ----
template<int K, int N>
__device__ __forceinline__ void xw_body(char* smem, const float* __restrict__ X,
                                        const float* __restrict__ W,
                                        float* __restrict__ Y, int bb) {
  constexpr int TPR = N / 4;
  constexpr int ROWS = 256 / TPR;
  constexpr int KC = (K * N * 4 > 16384) ? (16384 / (N * 4)) : K;
  float* Wl = (float*)smem;
  int r = bb * ROWS + threadIdx.x / TPR;
  int c4 = (threadIdx.x % TPR) * 4;
  float a0 = 0, a1 = 0, a2 = 0, a3 = 0;
#pragma unroll 1
  for (int k0 = 0; k0 < K; k0 += KC) {
    for (int t = threadIdx.x; t < KC * N / 4; t += 256)
      ((float4*)Wl)[t] = ((const float4*)(W + k0 * N))[t];
    __syncthreads();
    if (r < NN) {
      const float4* xr4 = (const float4*)(X + (size_t)r * K + k0);
#pragma unroll 4
      for (int k4 = 0; k4 < KC / 4; k4++) {
        float4 xv = xr4[k4];
        int kb = k4 * 4;
        { const float4 w = *(const float4*)&Wl[(kb + 0) * N + c4];
          a0 = fmaf(xv.x, w.x, a0); a1 = fmaf(xv.x, w.y, a1); a2 = fmaf(xv.x, w.z, a2); a3 = fmaf(xv.x, w.w, a3); }
        { const float4 w = *(const float4*)&Wl[(kb + 1) * N + c4];
          a0 = fmaf(xv.y, w.x, a0); a1 = fmaf(xv.y, w.y, a1); a2 = fmaf(xv.y, w.z, a2); a3 = fmaf(xv.y, w.w, a3); }
        { const float4 w = *(const float4*)&Wl[(kb + 2) * N + c4];
          a0 = fmaf(xv.z, w.x, a0); a1 = fmaf(xv.z, w.y, a1); a2 = fmaf(xv.z, w.z, a2); a3 = fmaf(xv.z, w.w, a3); }
        { const float4 w = *(const float4*)&Wl[(kb + 3) * N + c4];
          a0 = fmaf(xv.w, w.x, a0); a1 = fmaf(xv.w, w.y, a1); a2 = fmaf(xv.w, w.z, a2); a3 = fmaf(xv.w, w.w, a3); }
      }
    }
    __syncthreads();  // Wl reuse (next chunk / next tile)
  }
  if (r < NN) {
    float4 o; o.x = a0; o.y = a1; o.z = a2; o.w = a3;
    *(float4*)&Y[(size_t)r * N + c4] = o;
  }
}

// ---- Y(512x32) = X(512x512)@W(512x32), W streamed (no smem) ----
__device__ __forceinline__ void sk512_body(const float* X, const float* W, float* Y, int b) {
  int r = b * 32 + threadIdx.x / 8;
  int c4 = (threadIdx.x % 8) * 4;
  const float4* xr4 = (const float4*)(X + (size_t)r * 512);
  float a0 = 0, a1 = 0, a2 = 0, a3 = 0;
#pragma unroll 2
  for (int k4 = 0; k4 < 128; k4++) {
    float4 xv = xr4[k4];
    int kb = k4 * 4;
    { const float4 w = *(const float4*)&W[(kb + 0) * 32 + c4];
      a0 = fmaf(xv.x, w.x, a0); a1 = fmaf(xv.x, w.y, a1); a2 = fmaf(xv.x, w.z, a2); a3 = fmaf(xv.x, w.w, a3); }
    { const float4 w = *(const float4*)&W[(kb + 1) * 32 + c4];
      a0 = fmaf(xv.y, w.x, a0); a1 = fmaf(xv.y, w.y, a1); a2 = fmaf(xv.y, w.z, a2); a3 = fmaf(xv.y, w.w, a3); }
    { const float4 w = *(const float4*)&W[(kb + 2) * 32 + c4];
      a0 = fmaf(xv.z, w.x, a0); a1 = fmaf(xv.z, w.y, a1); a2 = fmaf(xv.z, w.z, a2); a3 = fmaf(xv.z, w.w, a3); }
    { const float4 w = *(const float4*)&W[(kb + 3) * 32 + c4];
      a0 = fmaf(xv.w, w.x, a0); a1 = fmaf(xv.w, w.y, a1); a2 = fmaf(xv.w, w.z, a2); a3 = fmaf(xv.w, w.w, a3); }
  }
  float4 o; o.x = a0; o.y = a1; o.z = a2; o.w = a3;
  *(float4*)&Y[(size_t)r * 32 + c4] = o;
}

// ================= phase bodies (one tile each; t-branches are block-uniform) =================

__device__ __forceinline__ void phase0(const Prm& p, char* smem, int t) {
  if (t < 128) {
    gemm512_body(smem, (t < 64) ? p.L0 : p.L1, (t < 64) ? p.L0r : p.L1r, t & 63);
  } else if (t < 1378) {
    xw_body<128, 64>(smem, p.x, p.W1, p.h1raw, t - 128);
  } else {
    int i = (t - 1378) * 256 + threadIdx.x;
    if (i < NN) p.ideg[i] = 0;
  }
}

__device__ __forceinline__ void phase1(const Prm& p, int t) {
  if (t < 16) sk512_body(p.L0r, p.wL0, p.Ab, t);
  else if (t < 32) sk512_body(p.L1r, p.wL1, p.Bb, t - 16);
  else {
    int e = (t - 32) * 256 + threadIdx.x;
    if (e < NE) atomicAdd(&p.ideg[p.ei[NE + e]], 1);
  }
}

__device__ __forceinline__ void phase2(const Prm& p, char* smem, int t) {
  int tid = threadIdx.x;
  if (t < 16) { sk512_body(p.wod, p.Ab, p.Ab2, t); return; }
  // exclusive scan over 20000 degrees: 256 thr x 80 contiguous ints, loads all in flight
  int* wsum = (int*)smem;
  int base = tid * 80;
  int4 c[20];
  int s = 0;
  if (base < NN) {
    const int4* ip = (const int4*)p.ideg + tid * 20;
#pragma unroll
    for (int i = 0; i < 20; i++) c[i] = ip[i];
#pragma unroll
    for (int i = 0; i < 20; i++) s += c[i].x + c[i].y + c[i].z + c[i].w;
  }
  int lane = tid & 63, wid = tid >> 6;
  int v = s;
#pragma unroll
  for (int o = 1; o < 64; o <<= 1) { int u = __shfl_up(v, o); if (lane >= o) v += u; }
  if (lane == 63) wsum[wid] = v;
  __syncthreads();
  int wbase = 0;
  for (int w = 0; w < wid; w++) wbase += wsum[w];
  int off = wbase + v - s;
  if (base < NN) {
#pragma unroll
    for (int i = 0; i < 20; i++) {
      int4 cc = c[i];
      int4 st;
      st.x = off; off += cc.x;
      st.y = off; off += cc.y;
      st.z = off; off += cc.z;
      st.w = off; off += cc.w;
      ((int4*)p.start)[tid * 20 + i] = st;
      ((int4*)p.cursor)[tid * 20 + i] = st;
      float4 dv;
      dv.x = rsqrtf((float)(cc.x + 1));
      dv.y = rsqrtf((float)(cc.y + 1));
      dv.z = rsqrtf((float)(cc.z + 1));
      dv.w = rsqrtf((float)(cc.w + 1));
      ((float4*)p.dinv)[tid * 20 + i] = dv;
    }
  }
  __syncthreads();
}

__device__ __forceinline__ void phase3(const Prm& p, char* smem, int t) {
  int tid = threadIdx.x;
  if (t >= 1024) {
    int e = (t - 1024) * 256 + tid;
    if (e < NE) {
      int d = p.ei[NE + e];
      int pos = atomicAdd(&p.cursor[d], 1);
      p.csr[pos] = p.ei[e];
    }
    return;
  }
  int i = t;
  float* smax = (float*)smem;
  float (*sred)[9] = (float(*)[9])(smem + 64);
  float urow[32];
  {
    const float4* up = (const float4*)((i < 512) ? (p.Ab2 + i * 32) : (p.Bb + (i - 512) * 32));
#pragma unroll
    for (int q = 0; q < 8; q++) {
      float4 u4 = up[q];
      urow[q * 4 + 0] = u4.x; urow[q * 4 + 1] = u4.y;
      urow[q * 4 + 2] = u4.z; urow[q * 4 + 3] = u4.w;
    }
  }
  float loc[4];
  float mymax = 0.0f;  // post-relu >= 0
#pragma unroll
  for (int tt = 0; tt < 4; tt++) {
    int j = tid + tt * 256;
    float v;
    if (i < 512) {
      if (j < 512) v = p.L0r[i * 512 + j];
      else {
        const float4* bj = (const float4*)(p.Bb + (j - 512) * 32);
        float acc = 0.0f;
#pragma unroll
        for (int q = 0; q < 8; q++) {
          float4 b4 = bj[q];
          acc = fmaf(urow[q * 4 + 0], b4.x, acc); acc = fmaf(urow[q * 4 + 1], b4.y, acc);
          acc = fmaf(urow[q * 4 + 2], b4.z, acc); acc = fmaf(urow[q * 4 + 3], b4.w, acc);
        }
        v = acc;
      }
    } else {
      int r = i - 512;
      if (j < 512) {
        const float4* aj = (const float4*)(p.Ab2 + j * 32);
        float acc = 0.0f;
#pragma unroll
        for (int q = 0; q < 8; q++) {
          float4 a4 = aj[q];
          acc = fmaf(urow[q * 4 + 0], a4.x, acc); acc = fmaf(urow[q * 4 + 1], a4.y, acc);
          acc = fmaf(urow[q * 4 + 2], a4.z, acc); acc = fmaf(urow[q * 4 + 3], a4.w, acc);
        }
        v = acc;
      } else v = p.L1r[r * 512 + (j - 512)];
    }
    v = fmaxf(v, 0.0f);
    loc[tt] = v;
    mymax = fmaxf(mymax, v);
  }
#pragma unroll
  for (int o = 32; o > 0; o >>= 1) mymax = fmaxf(mymax, __shfl_down(mymax, o));
  int wid = tid >> 6, lane = tid & 63;
  if (lane == 0) smax[wid] = mymax;
  __syncthreads();
  float m = fmaxf(fmaxf(smax[0], smax[1]), fmaxf(smax[2], smax[3]));

  float z = 0.0f, pm[8] = {};
#pragma unroll
  for (int tt = 0; tt < 4; tt++) {
    int j = tid + tt * 256;
    float e = __expf(loc[tt] - m);
    z += e;
    const float* wr = p.wsim + j * 8;
#pragma unroll
    for (int d = 0; d < 8; d++) pm[d] = fmaf(e, wr[d], pm[d]);
  }
#pragma unroll
  for (int o = 32; o > 0; o >>= 1) {
    z += __shfl_down(z, o);
#pragma unroll
    for (int d = 0; d < 8; d++) pm[d] += __shfl_down(pm[d], o);
  }
  if (lane == 0) {
    sred[wid][0] = z;
#pragma unroll
    for (int d = 0; d < 8; d++) sred[wid][1 + d] = pm[d];
  }
  __syncthreads();
  if (tid < 8) {
    float zt = sred[0][0] + sred[1][0] + sred[2][0] + sred[3][0];
    float pt = sred[0][1 + tid] + sred[1][1 + tid] + sred[2][1 + tid] + sred[3][1 + tid];
    p.Mm[i * 8 + tid] = pt / zt;
  }
  __syncthreads();  // smem reuse by next tile
}

__device__ __forceinline__ void phase4(const Prm& p, int t) {
  int tid = threadIdx.x;
  if (t < 5000) {
    int lane = tid & 63;
    int n = t * 4 + (tid >> 6);
    int s0 = p.start[n], cnt = p.ideg[n];
    float acc = 0.0f;
    int k = 0;
    for (; k + 1 < cnt; k += 2) {
      int sA = p.csr[s0 + k], sB = p.csr[s0 + k + 1];
      float dA = p.dinv[sA], dB = p.dinv[sB];
      float vA = p.h1raw[(size_t)sA * 64 + lane];
      float vB = p.h1raw[(size_t)sB * 64 + lane];
      acc = fmaf(vA, dA, acc);
      acc = fmaf(vB, dB, acc);
    }
    if (k < cnt) {
      int sA = p.csr[s0 + k];
      acc = fmaf(p.h1raw[(size_t)sA * 64 + lane], p.dinv[sA], acc);
    }
    float dn = p.dinv[n];
    float v = fmaf(acc, dn, p.h1raw[(size_t)n * 64 + lane] * dn * dn) + p.b1[lane];
    p.h1[(size_t)n * 64 + lane] = fmaxf(v, 0.0f);
  } else {
    int lane = tid & 63;
    int r = (t - 5000) * 4 + (tid >> 6);
    const float* er = p.embs + (size_t)r * 1024;
    float acc[8] = {};
    for (int it = 0; it < 16; it++) {
      int k = lane + it * 64;
      float e = er[k];
      const float4* mp = (const float4*)&p.Mm[k * 8];
      float4 m0 = mp[0], m1 = mp[1];
      acc[0] = fmaf(e, m0.x, acc[0]); acc[1] = fmaf(e, m0.y, acc[1]);
      acc[2] = fmaf(e, m0.z, acc[2]); acc[3] = fmaf(e, m0.w, acc[3]);
      acc[4] = fmaf(e, m1.x, acc[4]); acc[5] = fmaf(e, m1.y, acc[5]);
      acc[6] = fmaf(e, m1.z, acc[6]); acc[7] = fmaf(e, m1.w, acc[7]);
    }
#pragma unroll
    for (int o = 32; o > 0; o >>= 1)
#pragma unroll
      for (int d = 0; d < 8; d++) acc[d] += __shfl_down(acc[d], o);
    if (lane == 0)
#pragma unroll
      for (int d = 0; d < 8; d++) p.Ee[r * 8 + d] = acc[d];
  }
}

__device__ __forceinline__ void phase5(const Prm& p, char* smem, int t) {
  int tid = threadIdx.x;
  if (t < 625) {
    xw_body<64, 32>(smem, p.h1, p.W2, p.h1raw /*h2raw alias*/, t);
    return;
  }
  float* El = (float*)smem;
  for (int u = tid; u < 256; u += 256)
    ((float4*)El)[u] = ((const float4*)p.Ee)[u];
  __syncthreads();
  int row = (t - 625) * 256 + tid;
  if (row < NN) {
    const float4* xr4 = (const float4*)(p.x + (size_t)row * 128);
    float s[8] = {};
#pragma unroll 4
    for (int k4 = 0; k4 < 32; k4++) {
      float4 xv = xr4[k4];
      int kb = k4 * 4;
#pragma unroll
      for (int u = 0; u < 4; u++) {
        float xk = (u == 0) ? xv.x : (u == 1) ? xv.y : (u == 2) ? xv.z : xv.w;
        const float4* ep = (const float4*)&El[(kb + u) * 8];
        float4 e0 = ep[0], e1 = ep[1];
        s[0] = fmaf(xk, e0.x, s[0]); s[1] = fmaf(xk, e0.y, s[1]);
        s[2] = fmaf(xk, e0.z, s[2]); s[3] = fmaf(xk, e0.w, s[3]);
        s[4] = fmaf(xk, e1.x, s[4]); s[5] = fmaf(xk, e1.y, s[5]);
        s[6] = fmaf(xk, e1.z, s[6]); s[7] = fmaf(xk, e1.w, s[7]);
      }
    }
    float n2 = 0.0f;
#pragma unroll
    for (int d = 0; d < 8; d++) n2 += s[d] * s[d];
    float n = sqrtf(n2);
    float sc = (n > 1.0f) ? 1.0f / (n + 1e-7f) : 1.0f;
#pragma unroll
    for (int d = 0; d < 8; d++) p.semb[(size_t)row * 8 + d] = s[d] * sc;
  }
  __syncthreads();  // El reuse by next tile
}

__device__ __forceinline__ void phase6(const Prm& p, int t) {
  int tid = threadIdx.x;
  int lane = tid & 31;
  int n = t * 8 + (tid >> 5);
  int s0 = p.start[n], cnt = p.ideg[n];
  float acc = 0.0f;
  int k = 0;
  for (; k + 1 < cnt; k += 2) {
    int sA = p.csr[s0 + k], sB = p.csr[s0 + k + 1];
    float dA = p.dinv[sA], dB = p.dinv[sB];
    float vA = p.h1raw[(size_t)sA * 32 + lane];
    float vB = p.h1raw[(size_t)sB * 32 + lane];
    acc = fmaf(vA, dA, acc);
    acc = fmaf(vB, dB, acc);
  }
  if (k < cnt) {
    int sA = p.csr[s0 + k];
    acc = fmaf(p.h1raw[(size_t)sA * 32 + lane], p.dinv[sA], acc);
  }
  float dn = p.dinv[n];
  float v = fmaf(acc, dn, p.h1raw[(size_t)n * 32 + lane] * dn * dn) + p.b2[lane];
  v = fmaxf(v, 0.0f);
  float n2 = v * v;
#pragma unroll
  for (int o = 16; o > 0; o >>= 1) n2 += __shfl_xor(n2, o);
  float nrm = sqrtf(n2);
  float sc = (nrm > 1.0f) ? 1.0f / (nrm + 1e-7f) : 1.0f;
  p.g[(size_t)n * 32 + lane] = v * sc;
}

__device__ __forceinline__ void phase7(const Prm& p, int t) {
  int q = t * 256 + threadIdx.x;
  if (q >= NQ) return;
  const int2 pr = ((const int2*)p.te)[q];
  int i0 = pr.x, i1 = pr.y;
  float feat[40];
  const float4* g0 = (const float4*)(p.g + (size_t)i0 * 32);
  const float4* g1 = (const float4*)(p.g + (size_t)i1 * 32);
#pragma unroll
  for (int u = 0; u < 8; u++) {
    float4 a = g0[u], b = g1[u];
    float d0 = a.x - b.x, d1 = a.y - b.y, d2 = a.z - b.z, d3 = a.w - b.w;
    feat[u * 4 + 0] = d0 * d0; feat[u * 4 + 1] = d1 * d1;
    feat[u * 4 + 2] = d2 * d2; feat[u * 4 + 3] = d3 * d3;
  }
  const float4* s0 = (const float4*)(p.semb + (size_t)i0 * 8);
  const float4* s1 = (const float4*)(p.semb + (size_t)i1 * 8);
#pragma unroll
  for (int u = 0; u < 2; u++) {
    float4 a = s0[u], b = s1[u];
    float d0 = a.x - b.x, d1 = a.y - b.y, d2 = a.z - b.z, d3 = a.w - b.w;
    feat[32 + u * 4 + 0] = 0.1f * d0 * d0; feat[32 + u * 4 + 1] = 0.1f * d1 * d1;
    feat[32 + u * 4 + 2] = 0.1f * d2 * d2; feat[32 + u * 4 + 3] = 0.1f * d3 * d3;
  }
  float accv = p.linb[0];
#pragma unroll 1
  for (int h = 0; h < 2; h++) {  // two 16-col halves keep VGPR pressure low
    float acc[16];
#pragma unroll
    for (int c = 0; c < 16; c++) acc[c] = p.lin1b[h * 16 + c];
#pragma unroll
    for (int k = 0; k < 40; k++) {
      float f = feat[k];
#pragma unroll
      for (int c = 0; c < 16; c++)
        acc[c] = fmaf(f, p.lin1W[k * 32 + h * 16 + c], acc[c]);
    }
#pragma unroll
    for (int c = 0; c < 16; c++) {
      float a = acc[c];
      a = (a > 0.0f) ? a : 0.2f * a;
      accv = fmaf(a, p.linW[h * 16 + c], accv);
    }
  }
  float sq = fminf(fabsf(accv), 40.0f);
  p.out[q] = 1.0f / (1.0f + __expf(sq - 2.0f));
}

// ================= single cooperative kernel =================
__global__ __launch_bounds__(256, 4) void fused(Prm p) {
  cg::grid_group grid = cg::this_grid();
  __shared__ __align__(16) char smem[16384];
  const int NB = gridDim.x;
  for (int t = blockIdx.x; t < 1457; t += NB) phase0(p, smem, t);
  grid.sync();
  for (int t = blockIdx.x; t < 1282; t += NB) phase1(p, t);
  grid.sync();
  for (int t = blockIdx.x; t < 17; t += NB) phase2(p, smem, t);
  grid.sync();
  for (int t = blockIdx.x; t < 2274; t += NB) phase3(p, smem, t);
  grid.sync();
  for (int t = blockIdx.x; t < 5032; t += NB) phase4(p, t);
  grid.sync();
  for (int t = blockIdx.x; t < 704; t += NB) phase5(p, smem, t);
  grid.sync();
  for (int t = blockIdx.x; t < 2500; t += NB) phase6(p, t);
  grid.sync();
  for (int t = blockIdx.x; t < 782; t += NB) phase7(p, t);
}

// ================= fallback: one launch per phase =================
template<int PH>
__global__ __launch_bounds__(256, 4) void solo(Prm p) {
  __shared__ __align__(16) char smem[16384];
  int t = blockIdx.x;
  if (PH == 0) phase0(p, smem, t);
  if (PH == 1) phase1(p, t);
  if (PH == 2) phase2(p, smem, t);
  if (PH == 3) phase3(p, smem, t);
  if (PH == 4) phase4(p, t);
  if (PH == 5) phase5(p, smem, t);
  if (PH == 6) phase6(p, t);
  if (PH == 7) phase7(p, t);
}

extern "C" void kernel_launch(void* const* d_in, const int* in_sizes, int n_in,
                              void* d_out, int out_size, void* d_ws, size_t ws_size,
                              hipStream_t stream) {
  Prm p;
  p.x     = (const float*)d_in[0];
  p.L0    = (const float*)d_in[1];
  p.L1    = (const float*)d_in[2];
  p.ei    = (const int*)d_in[3];
  p.te    = (const int*)d_in[4];
  p.W1    = (const float*)d_in[5];
  p.b1    = (const float*)d_in[6];
  p.W2    = (const float*)d_in[7];
  p.b2    = (const float*)d_in[8];
  p.wsim  = (const float*)d_in[9];
  p.embs  = (const float*)d_in[10];
  p.wod   = (const float*)d_in[11];
  p.wL0   = (const float*)d_in[12];
  p.wL1   = (const float*)d_in[13];
  p.lin1W = (const float*)d_in[14];
  p.lin1b = (const float*)d_in[15];
  p.linW  = (const float*)d_in[16];
  p.linb  = (const float*)d_in[17];
  p.out   = (float*)d_out;

  p.ideg   = (int*)d_ws;                    // 20000
  p.start  = p.ideg + 20000;                // 20000
  p.cursor = p.start + 20000;               // 20000
  p.csr    = p.cursor + 20000;              // 320000
  p.dinv   = (float*)(p.csr + 320000);      // 20000
  p.h1raw  = p.dinv + 20000;                // 1,280,000 (reused as h2raw)
  p.h1     = p.h1raw + 1280000;             // 1,280,000
  p.g      = p.h1 + 1280000;                // 640,000
  p.L0r    = p.g + 640000;                  // 262,144
  p.L1r    = p.L0r + 262144;                // 262,144
  p.Ab     = p.L1r + 262144;                // 16,384
  p.Bb     = p.Ab + 16384;                  // 16,384
  p.Ab2    = p.Bb + 16384;                  // 16,384
  p.Mm     = p.Ab2 + 16384;                 // 8,192
  p.Ee     = p.Mm + 8192;                   // 1,024
  p.semb   = p.Ee + 1024;                   // 160,000

  // Ask the runtime how many blocks are co-resident, size the coop grid to fit.
  int occ = 0;
  hipError_t qe = hipOccupancyMaxActiveBlocksPerMultiprocessor(&occ, (const void*)fused, 256, 0);
  hipError_t le = hipErrorUnknown;
  if (qe == hipSuccess && occ > 0) {
    int grid = occ * 256;              // 256 CUs on MI355X
    if (grid > 1024) grid = 1024;
    void* args[] = { &p };
    le = hipLaunchCooperativeKernel((const void*)fused, dim3(grid), dim3(256), args, 0, stream);
  }
  if (le != hipSuccess) {
    // deterministic fallback: same phase bodies, 8 ordinary launches
    solo<0><<<1457, 256, 0, stream>>>(p);
    solo<1><<<1282, 256, 0, stream>>>(p);
    solo<2><<<17,   256, 0, stream>>>(p);
    solo<3><<<2274, 256, 0, stream>>>(p);
    solo<4><<<5032, 256, 0, stream>>>(p);
    solo<5><<<704,  256, 0, stream>>>(p);
    solo<6><<<2500, 256, 0, stream>>>(p);
    solo<7><<<782,  256, 0, stream>>>(p);
  }
}

// Round 7
// 157.435 us; speedup vs baseline: 4.2475x; 4.2475x over previous
//
#include <hip/hip_runtime.h>
#include <math.h>

#define NE 320000
#define NN 20000
#define NQ 200000

struct Prm {
  const float *x, *L0, *L1;
  const int *ei, *te;
  const float *W1, *b1, *W2, *b2, *wsim, *embs, *wod, *wL0, *wL1, *lin1W, *lin1b, *linW, *linb;
  float *out;
  int *ideg, *start, *cursor, *csr;
  float *dinv, *h1raw, *h2raw, *g, *L0r, *L1r, *U, *V0, *V1, *Ab2, *Bb, *Mm, *Ee, *semb;
};

// ---- 512^3 f32 GEMM tile: C = A@B, 64x64 tile, 4x4 microtile ----
__device__ __forceinline__ void gemm512_ab(char* smem, const float* __restrict__ A,
                                           const float* __restrict__ B,
                                           float* __restrict__ C, int bb) {
  float (*As)[68] = (float(*)[68])smem;
  float (*Bs)[68] = (float(*)[68])(smem + 16 * 68 * 4);
  int tid = threadIdx.x;
  int tx = tid & 15, ty = tid >> 4;
  int brow = (bb >> 3) * 64;
  int bcol = (bb & 7) * 64;
  float c[4][4] = {};
  for (int k0 = 0; k0 < 512; k0 += 16) {
#pragma unroll
    for (int t = 0; t < 4; t++) {
      int idx = tid * 4 + t;
      int r = idx >> 4, cc = idx & 15;
      As[cc][r] = A[(size_t)(brow + r) * 512 + k0 + cc];
      int r2 = idx >> 6, c2 = idx & 63;
      Bs[r2][c2] = B[(size_t)(k0 + r2) * 512 + bcol + c2];
    }
    __syncthreads();
#pragma unroll
    for (int k = 0; k < 16; k++) {
      float a0 = As[k][ty * 4 + 0], a1 = As[k][ty * 4 + 1];
      float a2 = As[k][ty * 4 + 2], a3 = As[k][ty * 4 + 3];
      float b0 = Bs[k][tx * 4 + 0], b1 = Bs[k][tx * 4 + 1];
      float b2 = Bs[k][tx * 4 + 2], b3 = Bs[k][tx * 4 + 3];
      c[0][0] = fmaf(a0, b0, c[0][0]); c[0][1] = fmaf(a0, b1, c[0][1]);
      c[0][2] = fmaf(a0, b2, c[0][2]); c[0][3] = fmaf(a0, b3, c[0][3]);
      c[1][0] = fmaf(a1, b0, c[1][0]); c[1][1] = fmaf(a1, b1, c[1][1]);
      c[1][2] = fmaf(a1, b2, c[1][2]); c[1][3] = fmaf(a1, b3, c[1][3]);
      c[2][0] = fmaf(a2, b0, c[2][0]); c[2][1] = fmaf(a2, b1, c[2][1]);
      c[2][2] = fmaf(a2, b2, c[2][2]); c[2][3] = fmaf(a2, b3, c[2][3]);
      c[3][0] = fmaf(a3, b0, c[3][0]); c[3][1] = fmaf(a3, b1, c[3][1]);
      c[3][2] = fmaf(a3, b2, c[3][2]); c[3][3] = fmaf(a3, b3, c[3][3]);
    }
    __syncthreads();
  }
#pragma unroll
  for (int i = 0; i < 4; i++)
#pragma unroll
    for (int j = 0; j < 4; j++)
      C[(size_t)(brow + ty * 4 + i) * 512 + bcol + tx * 4 + j] = c[i][j];
}

// ---- skinny: Y(MxN)=X(MxK)@W(KxN), W staged in LDS, one tile per block ----
template<int K, int N>
__device__ __forceinline__ void xw_body(char* smem, const float* __restrict__ X,
                                        const float* __restrict__ W,
                                        float* __restrict__ Y, int bb) {
  constexpr int TPR = N / 4;
  constexpr int ROWS = 256 / TPR;
  float* Wl = (float*)smem;
  for (int t = threadIdx.x; t < K * N / 4; t += 256)
    ((float4*)Wl)[t] = ((const float4*)W)[t];
  __syncthreads();
  int r = bb * ROWS + threadIdx.x / TPR;
  int c4 = (threadIdx.x % TPR) * 4;
  if (r >= NN) return;
  const float4* xr4 = (const float4*)(X + (size_t)r * K);
  float a0 = 0, a1 = 0, a2 = 0, a3 = 0;
#pragma unroll 4
  for (int k4 = 0; k4 < K / 4; k4++) {
    float4 xv = xr4[k4];
    int kb = k4 * 4;
    { const float4 w = *(const float4*)&Wl[(kb + 0) * N + c4];
      a0 = fmaf(xv.x, w.x, a0); a1 = fmaf(xv.x, w.y, a1); a2 = fmaf(xv.x, w.z, a2); a3 = fmaf(xv.x, w.w, a3); }
    { const float4 w = *(const float4*)&Wl[(kb + 1) * N + c4];
      a0 = fmaf(xv.y, w.x, a0); a1 = fmaf(xv.y, w.y, a1); a2 = fmaf(xv.y, w.z, a2); a3 = fmaf(xv.y, w.w, a3); }
    { const float4 w = *(const float4*)&Wl[(kb + 2) * N + c4];
      a0 = fmaf(xv.z, w.x, a0); a1 = fmaf(xv.z, w.y, a1); a2 = fmaf(xv.z, w.z, a2); a3 = fmaf(xv.z, w.w, a3); }
    { const float4 w = *(const float4*)&Wl[(kb + 3) * N + c4];
      a0 = fmaf(xv.w, w.x, a0); a1 = fmaf(xv.w, w.y, a1); a2 = fmaf(xv.w, w.z, a2); a3 = fmaf(xv.w, w.w, a3); }
  }
  float4 o; o.x = a0; o.y = a1; o.z = a2; o.w = a3;
  *(float4*)&Y[(size_t)r * N + c4] = o;
}

// ---- Y(512x32) = X(512x512)@W(512x32), W streamed ----
__device__ __forceinline__ void sk512_body(const float* X, const float* W, float* Y, int b) {
  int r = b * 32 + threadIdx.x / 8;
  int c4 = (threadIdx.x % 8) * 4;
  const float4* xr4 = (const float4*)(X + (size_t)r * 512);
  float a0 = 0, a1 = 0, a2 = 0, a3 = 0;
#pragma unroll 2
  for (int k4 = 0; k4 < 128; k4++) {
    float4 xv = xr4[k4];
    int kb = k4 * 4;
    { const float4 w = *(const float4*)&W[(kb + 0) * 32 + c4];
      a0 = fmaf(xv.x, w.x, a0); a1 = fmaf(xv.x, w.y, a1); a2 = fmaf(xv.x, w.z, a2); a3 = fmaf(xv.x, w.w, a3); }
    { const float4 w = *(const float4*)&W[(kb + 1) * 32 + c4];
      a0 = fmaf(xv.y, w.x, a0); a1 = fmaf(xv.y, w.y, a1); a2 = fmaf(xv.y, w.z, a2); a3 = fmaf(xv.y, w.w, a3); }
    { const float4 w = *(const float4*)&W[(kb + 2) * 32 + c4];
      a0 = fmaf(xv.z, w.x, a0); a1 = fmaf(xv.z, w.y, a1); a2 = fmaf(xv.z, w.z, a2); a3 = fmaf(xv.z, w.w, a3); }
    { const float4 w = *(const float4*)&W[(kb + 3) * 32 + c4];
      a0 = fmaf(xv.w, w.x, a0); a1 = fmaf(xv.w, w.y, a1); a2 = fmaf(xv.w, w.z, a2); a3 = fmaf(xv.w, w.w, a3); }
  }
  float4 o; o.x = a0; o.y = a1; o.z = a2; o.w = a3;
  *(float4*)&Y[(size_t)r * 32 + c4] = o;
}

// ================= kernels =================

// K1: L0r,L1r,U=wod@L0 (gemm512 x3) | V0,V1 (skinny) | xw1 | hist
__global__ __launch_bounds__(256) void k1(Prm p) {
  __shared__ __align__(16) char smem[32768];
  int b = blockIdx.x;
  if (b < 64)        gemm512_ab(smem, p.L0, p.L0, p.L0r, b);
  else if (b < 128)  gemm512_ab(smem, p.L1, p.L1, p.L1r, b - 64);
  else if (b < 192)  gemm512_ab(smem, p.wod, p.L0, p.U, b - 128);
  else if (b < 208)  sk512_body(p.L0, p.wL0, p.V0, b - 192);
  else if (b < 224)  sk512_body(p.L1, p.wL1, p.V1, b - 208);
  else if (b < 1474) xw_body<128, 64>(smem, p.x, p.W1, p.h1raw, b - 224);
  else {
    int e = (b - 1474) * 256 + threadIdx.x;
    if (e < NE) atomicAdd(&p.ideg[p.ei[NE + e]], 1);
  }
}

// K2: Ab2 = U@V0, Bb = L1@V1 | scan
__global__ __launch_bounds__(256) void k2(Prm p) {
  int b = blockIdx.x;
  if (b < 16) { sk512_body(p.U, p.V0, p.Ab2, b); return; }
  if (b < 32) { sk512_body(p.L1, p.V1, p.Bb, b - 16); return; }
  // exclusive scan over 20000 degrees: 256 thr x 80 contiguous ints, loads all in flight
  __shared__ int wsum[4];
  int tid = threadIdx.x;
  int base = tid * 80;
  int4 c[20];
  int s = 0;
  if (base < NN) {
    const int4* ip = (const int4*)p.ideg + tid * 20;
#pragma unroll
    for (int i = 0; i < 20; i++) c[i] = ip[i];
#pragma unroll
    for (int i = 0; i < 20; i++) s += c[i].x + c[i].y + c[i].z + c[i].w;
  }
  int lane = tid & 63, wid = tid >> 6;
  int v = s;
#pragma unroll
  for (int o = 1; o < 64; o <<= 1) { int u = __shfl_up(v, o); if (lane >= o) v += u; }
  if (lane == 63) wsum[wid] = v;
  __syncthreads();
  int wbase = 0;
  for (int w = 0; w < wid; w++) wbase += wsum[w];
  int off = wbase + v - s;
  if (base < NN) {
#pragma unroll
    for (int i = 0; i < 20; i++) {
      int4 cc = c[i];
      int4 st;
      st.x = off; off += cc.x;
      st.y = off; off += cc.y;
      st.z = off; off += cc.z;
      st.w = off; off += cc.w;
      ((int4*)p.start)[tid * 20 + i] = st;
      ((int4*)p.cursor)[tid * 20 + i] = st;
      float4 dv;
      dv.x = rsqrtf((float)(cc.x + 1));
      dv.y = rsqrtf((float)(cc.y + 1));
      dv.z = rsqrtf((float)(cc.z + 1));
      dv.w = rsqrtf((float)(cc.w + 1));
      ((float4*)p.dinv)[tid * 20 + i] = dv;
    }
  }
}

// K3: softmaxM with fused rel_ (blocks 0..1023) | scatter (1024..2273)
__global__ __launch_bounds__(256) void k3(Prm p) {
  int b = blockIdx.x;
  int tid = threadIdx.x;
  if (b >= 1024) {
    int e = (b - 1024) * 256 + tid;
    if (e < NE) {
      int d = p.ei[NE + e];
      int pos = atomicAdd(&p.cursor[d], 1);
      p.csr[pos] = p.ei[e];
    }
    return;
  }
  int i = b;
  __shared__ float smax[4];
  __shared__ float sred[4][9];
  float urow[32];
  {
    const float4* up = (const float4*)((i < 512) ? (p.Ab2 + i * 32) : (p.Bb + (i - 512) * 32));
#pragma unroll
    for (int q = 0; q < 8; q++) {
      float4 u4 = up[q];
      urow[q * 4 + 0] = u4.x; urow[q * 4 + 1] = u4.y;
      urow[q * 4 + 2] = u4.z; urow[q * 4 + 3] = u4.w;
    }
  }
  float loc[4];
  float mymax = 0.0f;  // post-relu >= 0
#pragma unroll
  for (int tt = 0; tt < 4; tt++) {
    int j = tid + tt * 256;
    float v;
    if (i < 512) {
      if (j < 512) v = p.L0r[i * 512 + j];
      else {
        const float4* bj = (const float4*)(p.Bb + (j - 512) * 32);
        float acc = 0.0f;
#pragma unroll
        for (int q = 0; q < 8; q++) {
          float4 b4 = bj[q];
          acc = fmaf(urow[q * 4 + 0], b4.x, acc); acc = fmaf(urow[q * 4 + 1], b4.y, acc);
          acc = fmaf(urow[q * 4 + 2], b4.z, acc); acc = fmaf(urow[q * 4 + 3], b4.w, acc);
        }
        v = acc;
      }
    } else {
      int r = i - 512;
      if (j < 512) {
        const float4* aj = (const float4*)(p.Ab2 + j * 32);
        float acc = 0.0f;
#pragma unroll
        for (int q = 0; q < 8; q++) {
          float4 a4 = aj[q];
          acc = fmaf(urow[q * 4 + 0], a4.x, acc); acc = fmaf(urow[q * 4 + 1], a4.y, acc);
          acc = fmaf(urow[q * 4 + 2], a4.z, acc); acc = fmaf(urow[q * 4 + 3], a4.w, acc);
        }
        v = acc;
      } else v = p.L1r[r * 512 + (j - 512)];
    }
    v = fmaxf(v, 0.0f);
    loc[tt] = v;
    mymax = fmaxf(mymax, v);
  }
#pragma unroll
  for (int o = 32; o > 0; o >>= 1) mymax = fmaxf(mymax, __shfl_down(mymax, o));
  int wid = tid >> 6, lane = tid & 63;
  if (lane == 0) smax[wid] = mymax;
  __syncthreads();
  float m = fmaxf(fmaxf(smax[0], smax[1]), fmaxf(smax[2], smax[3]));

  float z = 0.0f, pm[8] = {};
#pragma unroll
  for (int tt = 0; tt < 4; tt++) {
    int j = tid + tt * 256;
    float e = __expf(loc[tt] - m);
    z += e;
    const float* wr = p.wsim + j * 8;
#pragma unroll
    for (int d = 0; d < 8; d++) pm[d] = fmaf(e, wr[d], pm[d]);
  }
#pragma unroll
  for (int o = 32; o > 0; o >>= 1) {
    z += __shfl_down(z, o);
#pragma unroll
    for (int d = 0; d < 8; d++) pm[d] += __shfl_down(pm[d], o);
  }
  if (lane == 0) {
    sred[wid][0] = z;
#pragma unroll
    for (int d = 0; d < 8; d++) sred[wid][1 + d] = pm[d];
  }
  __syncthreads();
  if (tid < 8) {
    float zt = sred[0][0] + sred[1][0] + sred[2][0] + sred[3][0];
    float pt = sred[0][1 + tid] + sred[1][1 + tid] + sred[2][1 + tid] + sred[3][1 + tid];
    p.Mm[i * 8 + tid] = pt / zt;
  }
}

// K4: gather64 (float4 slots, 4 neighbors in flight) + fused xw2 | E
__global__ __launch_bounds__(256) void k4(Prm p) {
  __shared__ float W2l[64 * 32];
  __shared__ float h1l[4][64];
  int b = blockIdx.x;
  int tid = threadIdx.x;
  if (b < 5000) {
    // stage W2 (64x32) once per block
    for (int u = tid; u < 512; u += 256)
      ((float4*)W2l)[u] = ((const float4*)p.W2)[u];
    __syncthreads();
    int w = tid >> 6;          // wave = node slot
    int lane = tid & 63;
    int slot = lane >> 4;      // 4 neighbor slots
    int fi = lane & 15;        // feature quad
    int n = b * 4 + w;
    int s0 = p.start[n], cnt = p.ideg[n];
    float4 acc = {0.f, 0.f, 0.f, 0.f};
    for (int k = 0; k < cnt; k += 4) {
      int kk = k + slot;
      bool valid = kk < cnt;
      int src = valid ? p.csr[s0 + kk] : n;
      float wgt = valid ? p.dinv[src] : 0.0f;
      float4 v = ((const float4*)(p.h1raw + (size_t)src * 64))[fi];
      acc.x = fmaf(v.x, wgt, acc.x); acc.y = fmaf(v.y, wgt, acc.y);
      acc.z = fmaf(v.z, wgt, acc.z); acc.w = fmaf(v.w, wgt, acc.w);
    }
    // butterfly-reduce across the 4 slots
    acc.x += __shfl_xor(acc.x, 16); acc.y += __shfl_xor(acc.y, 16);
    acc.z += __shfl_xor(acc.z, 16); acc.w += __shfl_xor(acc.w, 16);
    acc.x += __shfl_xor(acc.x, 32); acc.y += __shfl_xor(acc.y, 32);
    acc.z += __shfl_xor(acc.z, 32); acc.w += __shfl_xor(acc.w, 32);
    float dn = p.dinv[n];
    float4 self = ((const float4*)(p.h1raw + (size_t)n * 64))[fi];
    float4 b1q = ((const float4*)p.b1)[fi];
    float4 h;
    h.x = fmaxf(fmaf(acc.x, dn, self.x * dn * dn) + b1q.x, 0.0f);
    h.y = fmaxf(fmaf(acc.y, dn, self.y * dn * dn) + b1q.y, 0.0f);
    h.z = fmaxf(fmaf(acc.z, dn, self.z * dn * dn) + b1q.z, 0.0f);
    h.w = fmaxf(fmaf(acc.w, dn, self.w * dn * dn) + b1q.w, 0.0f);
    if (slot == 0) ((float4*)h1l[w])[fi] = h;
    __syncthreads();
    // fused xw2: h2raw[n][c] = sum_k h1l[w][k] * W2[k][c]
    int c = lane & 31, half = lane >> 5;
    float s = 0.0f;
    const float* hr = h1l[w];
#pragma unroll
    for (int kk2 = 0; kk2 < 32; kk2++) {
      int k = half * 32 + kk2;
      s = fmaf(hr[k], W2l[k * 32 + c], s);
    }
    s += __shfl_xor(s, 32);
    if (half == 0) p.h2raw[(size_t)n * 32 + c] = s;
    return;
  }
  // ---- E(128x8) = embs(128x1024) @ Mm(1024x8) ----
  int lane = tid & 63;
  int r = (b - 5000) * 4 + (tid >> 6);
  const float* er = p.embs + (size_t)r * 1024;
  float acc[8] = {};
  for (int it = 0; it < 16; it++) {
    int k = lane + it * 64;
    float e = er[k];
    const float4* mp = (const float4*)&p.Mm[k * 8];
    float4 m0 = mp[0], m1 = mp[1];
    acc[0] = fmaf(e, m0.x, acc[0]); acc[1] = fmaf(e, m0.y, acc[1]);
    acc[2] = fmaf(e, m0.z, acc[2]); acc[3] = fmaf(e, m0.w, acc[3]);
    acc[4] = fmaf(e, m1.x, acc[4]); acc[5] = fmaf(e, m1.y, acc[5]);
    acc[6] = fmaf(e, m1.z, acc[6]); acc[7] = fmaf(e, m1.w, acc[7]);
  }
#pragma unroll
  for (int o = 32; o > 0; o >>= 1)
#pragma unroll
    for (int d = 0; d < 8; d++) acc[d] += __shfl_down(acc[d], o);
  if (lane == 0)
#pragma unroll
    for (int d = 0; d < 8; d++) p.Ee[r * 8 + d] = acc[d];
}

// K5: gather32 (8 slots) + renorm | semb
__global__ __launch_bounds__(256) void k5(Prm p) {
  __shared__ float El[1024];
  int b = blockIdx.x;
  int tid = threadIdx.x;
  if (b < 5000) {
    int w = tid >> 6;
    int lane = tid & 63;
    int slot = lane >> 3;   // 8 neighbor slots
    int fi = lane & 7;      // feature quad
    int n = b * 4 + w;
    int s0 = p.start[n], cnt = p.ideg[n];
    float4 acc = {0.f, 0.f, 0.f, 0.f};
    for (int k = 0; k < cnt; k += 8) {
      int kk = k + slot;
      bool valid = kk < cnt;
      int src = valid ? p.csr[s0 + kk] : n;
      float wgt = valid ? p.dinv[src] : 0.0f;
      float4 v = ((const float4*)(p.h2raw + (size_t)src * 32))[fi];
      acc.x = fmaf(v.x, wgt, acc.x); acc.y = fmaf(v.y, wgt, acc.y);
      acc.z = fmaf(v.z, wgt, acc.z); acc.w = fmaf(v.w, wgt, acc.w);
    }
    acc.x += __shfl_xor(acc.x, 8);  acc.y += __shfl_xor(acc.y, 8);
    acc.z += __shfl_xor(acc.z, 8);  acc.w += __shfl_xor(acc.w, 8);
    acc.x += __shfl_xor(acc.x, 16); acc.y += __shfl_xor(acc.y, 16);
    acc.z += __shfl_xor(acc.z, 16); acc.w += __shfl_xor(acc.w, 16);
    acc.x += __shfl_xor(acc.x, 32); acc.y += __shfl_xor(acc.y, 32);
    acc.z += __shfl_xor(acc.z, 32); acc.w += __shfl_xor(acc.w, 32);
    float dn = p.dinv[n];
    float4 self = ((const float4*)(p.h2raw + (size_t)n * 32))[fi];
    float4 b2q = ((const float4*)p.b2)[fi];
    float4 h;
    h.x = fmaxf(fmaf(acc.x, dn, self.x * dn * dn) + b2q.x, 0.0f);
    h.y = fmaxf(fmaf(acc.y, dn, self.y * dn * dn) + b2q.y, 0.0f);
    h.z = fmaxf(fmaf(acc.z, dn, self.z * dn * dn) + b2q.z, 0.0f);
    h.w = fmaxf(fmaf(acc.w, dn, self.w * dn * dn) + b2q.w, 0.0f);
    float n2 = h.x * h.x + h.y * h.y + h.z * h.z + h.w * h.w;
    n2 += __shfl_xor(n2, 1); n2 += __shfl_xor(n2, 2); n2 += __shfl_xor(n2, 4);
    float nrm = sqrtf(n2);
    float sc = (nrm > 1.0f) ? 1.0f / (nrm + 1e-7f) : 1.0f;
    if (slot == 0) {
      float4 o; o.x = h.x * sc; o.y = h.y * sc; o.z = h.z * sc; o.w = h.w * sc;
      ((float4*)(p.g + (size_t)n * 32))[fi] = o;
    }
    return;
  }
  // ---- semb = renorm(x @ Ee) ----
  for (int u = tid; u < 256; u += 256)
    ((float4*)El)[u] = ((const float4*)p.Ee)[u];
  __syncthreads();
  int row = (b - 5000) * 256 + tid;
  if (row >= NN) return;
  const float4* xr4 = (const float4*)(p.x + (size_t)row * 128);
  float s[8] = {};
#pragma unroll 4
  for (int k4 = 0; k4 < 32; k4++) {
    float4 xv = xr4[k4];
    int kb = k4 * 4;
#pragma unroll
    for (int u = 0; u < 4; u++) {
      float xk = (u == 0) ? xv.x : (u == 1) ? xv.y : (u == 2) ? xv.z : xv.w;
      const float4* ep = (const float4*)&El[(kb + u) * 8];
      float4 e0 = ep[0], e1 = ep[1];
      s[0] = fmaf(xk, e0.x, s[0]); s[1] = fmaf(xk, e0.y, s[1]);
      s[2] = fmaf(xk, e0.z, s[2]); s[3] = fmaf(xk, e0.w, s[3]);
      s[4] = fmaf(xk, e1.x, s[4]); s[5] = fmaf(xk, e1.y, s[5]);
      s[6] = fmaf(xk, e1.z, s[6]); s[7] = fmaf(xk, e1.w, s[7]);
    }
  }
  float n2 = 0.0f;
#pragma unroll
  for (int d = 0; d < 8; d++) n2 += s[d] * s[d];
  float n = sqrtf(n2);
  float sc = (n > 1.0f) ? 1.0f / (n + 1e-7f) : 1.0f;
#pragma unroll
  for (int d = 0; d < 8; d++) p.semb[(size_t)row * 8 + d] = s[d] * sc;
}

// K6: query head
__global__ __launch_bounds__(256) void k6(Prm p) {
  int q = blockIdx.x * 256 + threadIdx.x;
  if (q >= NQ) return;
  const int2 pr = ((const int2*)p.te)[q];
  int i0 = pr.x, i1 = pr.y;
  float feat[40];
  const float4* g0 = (const float4*)(p.g + (size_t)i0 * 32);
  const float4* g1 = (const float4*)(p.g + (size_t)i1 * 32);
#pragma unroll
  for (int u = 0; u < 8; u++) {
    float4 a = g0[u], b = g1[u];
    float d0 = a.x - b.x, d1 = a.y - b.y, d2 = a.z - b.z, d3 = a.w - b.w;
    feat[u * 4 + 0] = d0 * d0; feat[u * 4 + 1] = d1 * d1;
    feat[u * 4 + 2] = d2 * d2; feat[u * 4 + 3] = d3 * d3;
  }
  const float4* s0 = (const float4*)(p.semb + (size_t)i0 * 8);
  const float4* s1 = (const float4*)(p.semb + (size_t)i1 * 8);
#pragma unroll
  for (int u = 0; u < 2; u++) {
    float4 a = s0[u], b = s1[u];
    float d0 = a.x - b.x, d1 = a.y - b.y, d2 = a.z - b.z, d3 = a.w - b.w;
    feat[32 + u * 4 + 0] = 0.1f * d0 * d0; feat[32 + u * 4 + 1] = 0.1f * d1 * d1;
    feat[32 + u * 4 + 2] = 0.1f * d2 * d2; feat[32 + u * 4 + 3] = 0.1f * d3 * d3;
  }
  float acc[32];
#pragma unroll
  for (int c = 0; c < 32; c++) acc[c] = p.lin1b[c];
#pragma unroll
  for (int k = 0; k < 40; k++) {
    float f = feat[k];
#pragma unroll
    for (int c = 0; c < 32; c++) acc[c] = fmaf(f, p.lin1W[k * 32 + c], acc[c]);
  }
  float accv = p.linb[0];
#pragma unroll
  for (int c = 0; c < 32; c++) {
    float a = acc[c];
    a = (a > 0.0f) ? a : 0.2f * a;
    accv = fmaf(a, p.linW[c], accv);
  }
  float sq = fminf(fabsf(accv), 40.0f);
  p.out[q] = 1.0f / (1.0f + __expf(sq - 2.0f));
}

extern "C" void kernel_launch(void* const* d_in, const int* in_sizes, int n_in,
                              void* d_out, int out_size, void* d_ws, size_t ws_size,
                              hipStream_t stream) {
  Prm p;
  p.x     = (const float*)d_in[0];
  p.L0    = (const float*)d_in[1];
  p.L1    = (const float*)d_in[2];
  p.ei    = (const int*)d_in[3];
  p.te    = (const int*)d_in[4];
  p.W1    = (const float*)d_in[5];
  p.b1    = (const float*)d_in[6];
  p.W2    = (const float*)d_in[7];
  p.b2    = (const float*)d_in[8];
  p.wsim  = (const float*)d_in[9];
  p.embs  = (const float*)d_in[10];
  p.wod   = (const float*)d_in[11];
  p.wL0   = (const float*)d_in[12];
  p.wL1   = (const float*)d_in[13];
  p.lin1W = (const float*)d_in[14];
  p.lin1b = (const float*)d_in[15];
  p.linW  = (const float*)d_in[16];
  p.linb  = (const float*)d_in[17];
  p.out   = (float*)d_out;

  p.ideg   = (int*)d_ws;                    // 20000
  p.start  = p.ideg + 20000;                // 20000
  p.cursor = p.start + 20000;               // 20000
  p.csr    = p.cursor + 20000;              // 320000
  p.dinv   = (float*)(p.csr + 320000);      // 20000
  p.h1raw  = p.dinv + 20000;                // 1,280,000
  p.h2raw  = p.h1raw + 1280000;             // 640,000
  p.g      = p.h2raw + 640000;              // 640,000
  p.L0r    = p.g + 640000;                  // 262,144
  p.L1r    = p.L0r + 262144;                // 262,144
  p.U      = p.L1r + 262144;                // 262,144
  p.V0     = p.U + 262144;                  // 16,384
  p.V1     = p.V0 + 16384;                  // 16,384
  p.Ab2    = p.V1 + 16384;                  // 16,384
  p.Bb     = p.Ab2 + 16384;                 // 16,384
  p.Mm     = p.Bb + 16384;                  // 8,192
  p.Ee     = p.Mm + 8192;                   // 1,024
  p.semb   = p.Ee + 1024;                   // 160,000

  hipMemsetAsync(p.ideg, 0, 20000 * sizeof(int), stream);
  k1<<<2724, 256, 0, stream>>>(p);
  k2<<<33,   256, 0, stream>>>(p);
  k3<<<2274, 256, 0, stream>>>(p);
  k4<<<5032, 256, 0, stream>>>(p);
  k5<<<5079, 256, 0, stream>>>(p);
  k6<<<782,  256, 0, stream>>>(p);
}